// Round 1
// baseline (626.074 us; speedup 1.0000x reference)
//
#include <hip/hip_runtime.h>
#include <stdint.h>
#include <math.h>

// ---------------------------------------------------------------------------
// Problem constants (B,S,D,G fixed by the reference)
// ---------------------------------------------------------------------------
#define B_ 32
#define S_ 4096
#define D_ 512
#define G_ 128
#define MROWS (B_ * S_)                       // 131072 rows of h
#define NTOT (16777216.0)                     // B*S*G element count (double)

// JAX threefry_partitionable default is True on modern JAX (>=0.4.36).
// If validation shows a *structured* total mismatch, flip this to 0.
#define PARTITIONABLE 1

// ---------------------------------------------------------------------------
// threefry2x32 (Skein rotation schedule, 20 rounds) — matches JAX exactly
// ---------------------------------------------------------------------------
__host__ __device__ __forceinline__ uint32_t rotl32(uint32_t x, int r) {
  return (x << r) | (x >> (32 - r));
}

__host__ __device__ __forceinline__ void threefry2x32(
    uint32_t k0, uint32_t k1, uint32_t x0, uint32_t x1,
    uint32_t& o0, uint32_t& o1) {
  const uint32_t ks2 = k0 ^ k1 ^ 0x1BD11BDAu;
  uint32_t v0 = x0 + k0;
  uint32_t v1 = x1 + k1;
#define TF_RND(r) { v0 += v1; v1 = rotl32(v1, (r)); v1 ^= v0; }
  TF_RND(13) TF_RND(15) TF_RND(26) TF_RND(6)
  v0 += k1;  v1 += ks2 + 1u;
  TF_RND(17) TF_RND(29) TF_RND(16) TF_RND(24)
  v0 += ks2; v1 += k0 + 2u;
  TF_RND(13) TF_RND(15) TF_RND(26) TF_RND(6)
  v0 += k0;  v1 += k1 + 3u;
  TF_RND(17) TF_RND(29) TF_RND(16) TF_RND(24)
  v0 += k1;  v1 += ks2 + 4u;
  TF_RND(13) TF_RND(15) TF_RND(26) TF_RND(6)
  v0 += ks2; v1 += k0 + 5u;
#undef TF_RND
  o0 = v0; o1 = v1;
}

// uniform(0,1) bits -> float per JAX: bitcast(bits>>9 | 0x3f800000) - 1
__device__ __forceinline__ float bits_to_u01(uint32_t bits) {
  return __uint_as_float((bits >> 9) | 0x3f800000u) - 1.0f;
}

// dropout: keep iff u < 0.9f ; kept value = x / 0.9f (match XLA's divide)
__device__ __forceinline__ float drop_scale(uint32_t kd0, uint32_t kd1,
                                            uint32_t j, float xv) {
  uint32_t o0, o1;
#if PARTITIONABLE
  threefry2x32(kd0, kd1, 0u, j, o0, o1);
  uint32_t bits = o0 ^ o1;
#else
  const uint32_t half = 1u << 25;  // total elements 2^26
  uint32_t bits;
  if (j < half) { threefry2x32(kd0, kd1, j, j + half, o0, o1); bits = o0; }
  else          { threefry2x32(kd0, kd1, j - half, j, o0, o1); bits = o1; }
#endif
  float u = bits_to_u01(bits);
  return (u < 0.9f) ? (xv / 0.9f) : 0.0f;
}

// ---------------------------------------------------------------------------
// critic_mask dtype-agnostic accessor (mode: 0=int32, 1=uint8/bool, 2=float32)
// ---------------------------------------------------------------------------
__device__ __forceinline__ bool mask_at(const void* m, int mode, long long i) {
  if (mode == 0) return ((const int*)m)[i] != 0;
  if (mode == 1) return ((const unsigned char*)m)[i] != 0;
  return ((const float*)m)[i] != 0.0f;
}

// ---------------------------------------------------------------------------
// K1: h = dropout(x) @ W^T + b ; also accumulate sum(h), sum(h^2) in f64.
// BM=128, BN=128(=G), BK=32; 256 threads; 8x8 micro-tile per thread.
// ---------------------------------------------------------------------------
__global__ __launch_bounds__(256, 2) void k_matmul(
    const float* __restrict__ x, const float* __restrict__ Wm,
    const float* __restrict__ bias, float* __restrict__ h,
    double* __restrict__ sums, uint32_t kd0, uint32_t kd1)
{
  __shared__ float As[32][132];   // [k][row]
  __shared__ float Ws[32][144];   // [k][swizzled col]
  __shared__ double red[8];

  const int tid = threadIdx.x;
  const long long row0 = (long long)blockIdx.x * 128;

  float acc[8][8];
#pragma unroll
  for (int i = 0; i < 8; ++i)
#pragma unroll
    for (int j = 0; j < 8; ++j) acc[i][j] = 0.0f;

  // A loader: thread -> (row, 16-wide k half-chunk)
  const int arow = tid >> 1;
  const int ak0  = (tid & 1) << 4;
  // W loader: same shape over the 128 weight rows (cols of h)
  const int wc    = tid >> 1;
  const int wk0   = (tid & 1) << 4;
  const int wphys = wc + ((wc >> 5) << 2);  // bank-spread swizzle

  // compute-phase indices: 16x16 thread grid, 8 rows x 8 cols each
  const int tr = tid >> 4;
  const int tc = tid & 15;
  const int r0 = tr * 8;
  const int cbase = tc * 8 + ((tc >> 2) << 2);  // swizzled base of 8 cols
  const int c0 = tc * 8;                        // logical col base

  const float* xrow = x + (row0 + arow) * D_;
  const uint32_t jrow = (uint32_t)((row0 + arow) * D_);

  for (int kc = 0; kc < D_; kc += 32) {
    // --- stage A tile with inline threefry dropout ---
#pragma unroll
    for (int i4 = 0; i4 < 4; ++i4) {
      const int ko = ak0 + i4 * 4;
      float4 xv = *(const float4*)(xrow + kc + ko);
      uint32_t jb = jrow + (uint32_t)(kc + ko);
      As[ko + 0][arow] = drop_scale(kd0, kd1, jb + 0u, xv.x);
      As[ko + 1][arow] = drop_scale(kd0, kd1, jb + 1u, xv.y);
      As[ko + 2][arow] = drop_scale(kd0, kd1, jb + 2u, xv.z);
      As[ko + 3][arow] = drop_scale(kd0, kd1, jb + 3u, xv.w);
    }
    // --- stage W tile (swizzled columns) ---
#pragma unroll
    for (int i4 = 0; i4 < 4; ++i4) {
      const int ko = wk0 + i4 * 4;
      float4 wv = *(const float4*)(Wm + wc * D_ + kc + ko);
      Ws[ko + 0][wphys] = wv.x;
      Ws[ko + 1][wphys] = wv.y;
      Ws[ko + 2][wphys] = wv.z;
      Ws[ko + 3][wphys] = wv.w;
    }
    __syncthreads();

#pragma unroll 8
    for (int kk = 0; kk < 32; ++kk) {
      float4 a0 = *(const float4*)&As[kk][r0];
      float4 a1 = *(const float4*)&As[kk][r0 + 4];
      float4 b0 = *(const float4*)&Ws[kk][cbase];
      float4 b1 = *(const float4*)&Ws[kk][cbase + 4];
      float av[8] = {a0.x, a0.y, a0.z, a0.w, a1.x, a1.y, a1.z, a1.w};
      float bv[8] = {b0.x, b0.y, b0.z, b0.w, b1.x, b1.y, b1.z, b1.w};
#pragma unroll
      for (int i = 0; i < 8; ++i)
#pragma unroll
        for (int j = 0; j < 8; ++j)
          acc[i][j] = fmaf(av[i], bv[j], acc[i][j]);
    }
    __syncthreads();
  }

  // --- epilogue: + bias, write h, f64 sum/sumsq ---
  double s1 = 0.0, s2 = 0.0;
  float bvals[8];
#pragma unroll
  for (int j = 0; j < 8; ++j) bvals[j] = bias[c0 + j];
#pragma unroll
  for (int i = 0; i < 8; ++i) {
    const long long grow = row0 + r0 + i;
    float tmp[8];
#pragma unroll
    for (int j = 0; j < 8; ++j) {
      float v = acc[i][j] + bvals[j];
      tmp[j] = v;
      s1 += (double)v;
      s2 += (double)v * (double)v;
    }
    *(float4*)(h + grow * G_ + c0)     = make_float4(tmp[0], tmp[1], tmp[2], tmp[3]);
    *(float4*)(h + grow * G_ + c0 + 4) = make_float4(tmp[4], tmp[5], tmp[6], tmp[7]);
  }
#pragma unroll
  for (int off = 32; off > 0; off >>= 1) {
    s1 += __shfl_down(s1, off);
    s2 += __shfl_down(s2, off);
  }
  const int lane = tid & 63, wid = tid >> 6;
  if (lane == 0) { red[wid * 2] = s1; red[wid * 2 + 1] = s2; }
  __syncthreads();
  if (tid == 0) {
    double t1 = red[0] + red[2] + red[4] + red[6];
    double t2 = red[1] + red[3] + red[5] + red[7];
    atomicAdd(&sums[0], t1);
    atomicAdd(&sums[1], t2);
  }
}

// ---------------------------------------------------------------------------
// K2: one block, 128 threads: noise[g] = 0.5*mean + std*N_g  (+ mask dtype probe)
// ---------------------------------------------------------------------------
__global__ void k_noise(const void* __restrict__ mask,
                        const double* __restrict__ sums,
                        float* __restrict__ noise, int* __restrict__ mode_p,
                        uint32_t kn0, uint32_t kn1)
{
  const int g = threadIdx.x;  // 0..127
  const double S1 = sums[0], S2 = sums[1];
  const float meanf = (float)(S1 / NTOT);
  const double var = (S2 - S1 * S1 / NTOT) / (NTOT - 1.0);
  const float stdf = (float)sqrt(var);
  const float mean_s = meanf / 10.0f;  // MEAN_FACTOR
  const float std_s  = stdf / 5.0f;    // STD_FACTOR

  uint32_t o0, o1, bits;
#if PARTITIONABLE
  threefry2x32(kn0, kn1, 0u, (uint32_t)g, o0, o1);
  bits = o0 ^ o1;
#else
  if (g < 64) { threefry2x32(kn0, kn1, (uint32_t)g, (uint32_t)(g + 64), o0, o1); bits = o0; }
  else        { threefry2x32(kn0, kn1, (uint32_t)(g - 64), (uint32_t)g, o0, o1); bits = o1; }
#endif
  // jax.random.normal: u in (-1,1), sqrt(2)*erfinv(u)
  float u = bits_to_u01(bits);
  float v = u * 2.0f + (-0.99999994f);
  v = fmaxf(v, -0.99999994f);
  float wv = -log1pf(-v * v);
  float p;
  if (wv < 5.0f) {
    wv -= 2.5f;
    p = 2.81022636e-08f;
    p = fmaf(p, wv, 3.43273939e-07f);
    p = fmaf(p, wv, -3.5233877e-06f);
    p = fmaf(p, wv, -4.39150654e-06f);
    p = fmaf(p, wv, 0.00021858087f);
    p = fmaf(p, wv, -0.00125372503f);
    p = fmaf(p, wv, -0.00417768164f);
    p = fmaf(p, wv, 0.246640727f);
    p = fmaf(p, wv, 1.50140941f);
  } else {
    wv = sqrtf(wv) - 3.0f;
    p = -0.000200214257f;
    p = fmaf(p, wv, 0.000100950558f);
    p = fmaf(p, wv, 0.00134934322f);
    p = fmaf(p, wv, -0.00367342844f);
    p = fmaf(p, wv, 0.00573950773f);
    p = fmaf(p, wv, -0.0076224613f);
    p = fmaf(p, wv, 0.00943887047f);
    p = fmaf(p, wv, 1.00167406f);
    p = fmaf(p, wv, 2.83297682f);
  }
  const float nrm = 1.41421354f * (p * v);
  noise[g] = mean_s + std_s * nrm - 0.5f * mean_s;

  if (g == 0) {
    // probe critic_mask storage: int32 (all u32 words <=1) vs float32 vs bytes
    const uint32_t* wm = (const uint32_t*)mask;
    bool all01 = true, allf = true;
    for (int i = 0; i < 64; ++i) {
      uint32_t w = wm[i];
      if (w > 1u) all01 = false;
      if (w != 0u && w != 0x3f800000u) allf = false;
    }
    *mode_p = all01 ? 0 : (allf ? 2 : 1);
  }
}

// ---------------------------------------------------------------------------
// K3: add noise to segment-START rows only (in place). Sources stay fixed
// points for the later gather, making in-place forward-fill race-free.
// ---------------------------------------------------------------------------
__global__ void k_addnoise(float* __restrict__ h, const void* __restrict__ mask,
                           const float* __restrict__ noise,
                           const int* __restrict__ mode_p)
{
  const int mode = *mode_p;
  const long long idx4 = (long long)blockIdx.x * blockDim.x + threadIdx.x;
  const long long row = idx4 >> 5;        // 32 float4 per row of G=128
  const int t = (int)(row & (S_ - 1));
  const long long b = row >> 12;
  const bool start = (t == 0) || mask_at(mask, mode, b * S_ + t - 1);
  if (!start) return;
  const int c4 = (int)(idx4 & 31);
  const float4 nv = ((const float4*)noise)[c4];
  float4 v = ((float4*)h)[idx4];
  v.x += nv.x; v.y += nv.y; v.z += nv.z; v.w += nv.w;
  ((float4*)h)[idx4] = v;
}

// ---------------------------------------------------------------------------
// K4: forward-fill gather, in place. Each half-wave (32 lanes) handles one row;
// backward walk to the segment start (E[len]~2, mask cached).
// ---------------------------------------------------------------------------
__global__ void k_fill(float* __restrict__ h, const void* __restrict__ mask,
                       const int* __restrict__ mode_p)
{
  const int mode = *mode_p;
  const long long row = (long long)blockIdx.x * 8 + (threadIdx.x >> 5);
  const int lane4 = threadIdx.x & 31;
  const int t = (int)(row & (S_ - 1));
  const long long b = row >> 12;
  const long long mbase = b * S_;
  int s = t;
  while (s > 0 && !mask_at(mask, mode, mbase + s - 1)) --s;
  if (s == t) return;  // start row: already noised, is a gather source
  const float4 v = ((const float4*)h)[(mbase + s) * 32 + lane4];
  ((float4*)h)[row * 32 + lane4] = v;
}

// ---------------------------------------------------------------------------
// host entry
// ---------------------------------------------------------------------------
extern "C" void kernel_launch(void* const* d_in, const int* in_sizes, int n_in,
                              void* d_out, int out_size, void* d_ws, size_t ws_size,
                              hipStream_t stream)
{
  (void)in_sizes; (void)n_in; (void)out_size; (void)ws_size;
  const float* x    = (const float*)d_in[0];
  const void*  mask = d_in[1];
  const float* Wm   = (const float*)d_in[2];
  const float* bias = (const float*)d_in[3];
  float* h = (float*)d_out;

  double* sums  = (double*)d_ws;                 // 16 B
  int*    modep = (int*)((char*)d_ws + 16);      // 4 B
  float*  noise = (float*)((char*)d_ws + 32);    // 512 B

  // derive kd/kn from jax.random.key(42) on the host (deterministic)
  uint32_t kd0, kd1, kn0, kn1;
#if PARTITIONABLE
  threefry2x32(0u, 42u, 0u, 0u, kd0, kd1);   // split "foldlike": key_i = tf(key,(0,i))
  threefry2x32(0u, 42u, 0u, 1u, kn0, kn1);
#else
  {
    uint32_t a0, a1, b0, b1;
    threefry2x32(0u, 42u, 0u, 2u, a0, b0);   // legacy split pairs (0,2),(1,3)
    threefry2x32(0u, 42u, 1u, 3u, a1, b1);
    kd0 = a0; kd1 = a1; kn0 = b0; kn1 = b1;
  }
#endif

  hipMemsetAsync(d_ws, 0, 16, stream);
  hipLaunchKernelGGL(k_matmul, dim3(MROWS / 128), dim3(256), 0, stream,
                     x, Wm, bias, h, sums, kd0, kd1);
  hipLaunchKernelGGL(k_noise, dim3(1), dim3(128), 0, stream,
                     mask, sums, noise, modep, kn0, kn1);
  hipLaunchKernelGGL(k_addnoise, dim3((MROWS * 32) / 256), dim3(256), 0, stream,
                     h, mask, noise, modep);
  hipLaunchKernelGGL(k_fill, dim3(MROWS / 8), dim3(256), 0, stream,
                     h, mask, modep);
}

// Round 4
// 521.065 us; speedup vs baseline: 1.2015x; 1.2015x over previous
//
#include <hip/hip_runtime.h>
#include <stdint.h>
#include <math.h>

#define B_ 32
#define S_ 4096
#define D_ 512
#define G_ 128
#define MROWS (B_ * S_)
#define NTOT (16777216.0)

#define PARTITIONABLE 1

typedef __attribute__((ext_vector_type(8))) short bf16x8;
typedef __attribute__((ext_vector_type(4))) float f32x4;

// ---------------------------------------------------------------------------
// threefry2x32 — matches JAX exactly
// ---------------------------------------------------------------------------
__host__ __device__ __forceinline__ uint32_t rotl32(uint32_t x, int r) {
  return (x << r) | (x >> (32 - r));
}

__host__ __device__ __forceinline__ void threefry2x32(
    uint32_t k0, uint32_t k1, uint32_t x0, uint32_t x1,
    uint32_t& o0, uint32_t& o1) {
  const uint32_t ks2 = k0 ^ k1 ^ 0x1BD11BDAu;
  uint32_t v0 = x0 + k0;
  uint32_t v1 = x1 + k1;
#define TF_RND(r) { v0 += v1; v1 = rotl32(v1, (r)); v1 ^= v0; }
  TF_RND(13) TF_RND(15) TF_RND(26) TF_RND(6)
  v0 += k1;  v1 += ks2 + 1u;
  TF_RND(17) TF_RND(29) TF_RND(16) TF_RND(24)
  v0 += ks2; v1 += k0 + 2u;
  TF_RND(13) TF_RND(15) TF_RND(26) TF_RND(6)
  v0 += k0;  v1 += k1 + 3u;
  TF_RND(17) TF_RND(29) TF_RND(16) TF_RND(24)
  v0 += k1;  v1 += ks2 + 4u;
  TF_RND(13) TF_RND(15) TF_RND(26) TF_RND(6)
  v0 += ks2; v1 += k0 + 5u;
#undef TF_RND
  o0 = v0; o1 = v1;
}

__device__ __forceinline__ float bits_to_u01(uint32_t bits) {
  return __uint_as_float((bits >> 9) | 0x3f800000u) - 1.0f;
}

__device__ __forceinline__ float drop_scale(uint32_t kd0, uint32_t kd1,
                                            uint32_t j, float xv) {
  uint32_t o0, o1;
  threefry2x32(kd0, kd1, 0u, j, o0, o1);
  uint32_t bits = o0 ^ o1;
  float u = bits_to_u01(bits);
  return (u < 0.9f) ? (xv / 0.9f) : 0.0f;
}

// round-to-nearest-even bf16 split: v = hi + lo (each stored as bf16 bits)
__device__ __forceinline__ void split_bf16(float v, ushort& hh, ushort& ll) {
  uint32_t u = __float_as_uint(v);
  uint32_t rh = (u + 0x7FFFu + ((u >> 16) & 1u)) >> 16;
  hh = (ushort)rh;
  float hf = __uint_as_float(rh << 16);
  float lf = v - hf;  // exact
  uint32_t ul = __float_as_uint(lf);
  ll = (ushort)((ul + 0x7FFFu + ((ul >> 16) & 1u)) >> 16);
}

// ---------------------------------------------------------------------------
// critic_mask dtype-agnostic accessor (mode: 0=int32, 1=uint8/bool, 2=float32)
// ---------------------------------------------------------------------------
__device__ __forceinline__ bool mask_at(const void* m, int mode, long long i) {
  if (mode == 0) return ((const int*)m)[i] != 0;
  if (mode == 1) return ((const unsigned char*)m)[i] != 0;
  return ((const float*)m)[i] != 0.0f;
}

__device__ __forceinline__ int probe_mode(const void* mask) {
  const uint32_t* wm = (const uint32_t*)mask;
  bool all01 = true, allf = true;
  for (int i = 0; i < 64; ++i) {
    uint32_t w = wm[i];
    if (w > 1u) all01 = false;
    if (w != 0u && w != 0x3f800000u) allf = false;
  }
  return all01 ? 0 : (allf ? 2 : 1);
}

// ---------------------------------------------------------------------------
// K1: h = dropout(x) @ W^T + b via bf16 3-pass split MFMA; f64 sum/sumsq.
// BM=128, BN=128(=G), BK=32; 256 threads = 4 waves, each wave 64x64 out.
// ---------------------------------------------------------------------------
__global__ __launch_bounds__(256, 2) void k_matmul(
    const float* __restrict__ x, const float* __restrict__ Wm,
    const float* __restrict__ bias, float* __restrict__ h,
    double* __restrict__ sums, uint32_t kd0, uint32_t kd1)
{
  __shared__ ushort AsH[128][40];   // [row][k] pad 32->40 (2-way max conflict)
  __shared__ ushort AsL[128][40];
  __shared__ ushort BsH[128][40];   // [g][k]
  __shared__ ushort BsL[128][40];
  __shared__ double red[8];

  const int tid = threadIdx.x;
  const long long row0 = (long long)blockIdx.x * 128;

  f32x4 acc[4][4];
#pragma unroll
  for (int m = 0; m < 4; ++m)
#pragma unroll
    for (int n = 0; n < 4; ++n) acc[m][n] = (f32x4)0.0f;

  // staging mapping: 2 threads per row, 16 k each
  const int arow = tid >> 1;
  const int ak0  = (tid & 1) << 4;
  const float* xrow = x + (row0 + arow) * D_ + ak0;
  const float* wrow = Wm + arow * D_ + ak0;
  const uint32_t jrow = (uint32_t)((row0 + arow) * D_) + (uint32_t)ak0;

  // compute mapping
  const int lane = tid & 63;
  const int wid  = tid >> 6;
  const int rbw  = (wid >> 1) * 64;
  const int cbw  = (wid & 1) * 64;
  const int lr   = lane & 15;
  const int lk   = (lane >> 4) * 8;

  float4 ax0, ax1, ax2, ax3, wx0, wx1, wx2, wx3;
#define LOADT(kc) { \
    const float4* xp = (const float4*)(xrow + (kc)); \
    const float4* wp = (const float4*)(wrow + (kc)); \
    ax0 = xp[0]; ax1 = xp[1]; ax2 = xp[2]; ax3 = xp[3]; \
    wx0 = wp[0]; wx1 = wp[1]; wx2 = wp[2]; wx3 = wp[3]; }

#define PROCA(xv, i4, kc) { \
    uint32_t jb = jrow + (uint32_t)(kc) + (uint32_t)((i4) * 4); \
    float v0 = drop_scale(kd0, kd1, jb + 0u, (xv).x); \
    float v1 = drop_scale(kd0, kd1, jb + 1u, (xv).y); \
    float v2 = drop_scale(kd0, kd1, jb + 2u, (xv).z); \
    float v3 = drop_scale(kd0, kd1, jb + 3u, (xv).w); \
    ushort h0,l0,h1,l1,h2,l2,h3,l3; \
    split_bf16(v0,h0,l0); split_bf16(v1,h1,l1); \
    split_bf16(v2,h2,l2); split_bf16(v3,h3,l3); \
    *(ushort4*)&AsH[arow][ak0 + (i4)*4] = make_ushort4(h0,h1,h2,h3); \
    *(ushort4*)&AsL[arow][ak0 + (i4)*4] = make_ushort4(l0,l1,l2,l3); }

#define PROCW(wv, i4) { \
    ushort h0,l0,h1,l1,h2,l2,h3,l3; \
    split_bf16((wv).x,h0,l0); split_bf16((wv).y,h1,l1); \
    split_bf16((wv).z,h2,l2); split_bf16((wv).w,h3,l3); \
    *(ushort4*)&BsH[arow][ak0 + (i4)*4] = make_ushort4(h0,h1,h2,h3); \
    *(ushort4*)&BsL[arow][ak0 + (i4)*4] = make_ushort4(l0,l1,l2,l3); }

  LOADT(0);
  for (int kc = 0; kc < D_; kc += 32) {
    // stage current chunk (threefry dropout on A; hi/lo split both)
    PROCA(ax0, 0, kc) PROCA(ax1, 1, kc) PROCA(ax2, 2, kc) PROCA(ax3, 3, kc)
    PROCW(wx0, 0) PROCW(wx1, 1) PROCW(wx2, 2) PROCW(wx3, 3)
    __syncthreads();
    if (kc + 32 < D_) LOADT(kc + 32);   // issue next-chunk loads early

    bf16x8 ah[4], al[4], bh[4], bl[4];
#pragma unroll
    for (int m = 0; m < 4; ++m) {
      ah[m] = *(const bf16x8*)&AsH[rbw + m * 16 + lr][lk];
      al[m] = *(const bf16x8*)&AsL[rbw + m * 16 + lr][lk];
    }
#pragma unroll
    for (int n = 0; n < 4; ++n) {
      bh[n] = *(const bf16x8*)&BsH[cbw + n * 16 + lr][lk];
      bl[n] = *(const bf16x8*)&BsL[cbw + n * 16 + lr][lk];
    }
#pragma unroll
    for (int m = 0; m < 4; ++m)
#pragma unroll
      for (int n = 0; n < 4; ++n) {
        acc[m][n] = __builtin_amdgcn_mfma_f32_16x16x32_bf16(ah[m], bh[n], acc[m][n], 0, 0, 0);
        acc[m][n] = __builtin_amdgcn_mfma_f32_16x16x32_bf16(ah[m], bl[n], acc[m][n], 0, 0, 0);
        acc[m][n] = __builtin_amdgcn_mfma_f32_16x16x32_bf16(al[m], bh[n], acc[m][n], 0, 0, 0);
      }
    __syncthreads();
  }
#undef LOADT
#undef PROCA
#undef PROCW

  // epilogue: +bias, store, f64 sums. C/D layout: col=lane&15, row=(lane>>4)*4+reg
  double s1 = 0.0, s2 = 0.0;
  const int orow_q = (lane >> 4) * 4;
  float bn[4];
#pragma unroll
  for (int n = 0; n < 4; ++n) bn[n] = bias[cbw + n * 16 + lr];
#pragma unroll
  for (int m = 0; m < 4; ++m) {
#pragma unroll
    for (int n = 0; n < 4; ++n) {
#pragma unroll
      for (int r = 0; r < 4; ++r) {
        const long long grow = row0 + rbw + m * 16 + orow_q + r;
        float v = acc[m][n][r] + bn[n];
        h[grow * G_ + cbw + n * 16 + lr] = v;
        s1 += (double)v;
        s2 += (double)v * (double)v;
      }
    }
  }
#pragma unroll
  for (int off = 32; off > 0; off >>= 1) {
    s1 += __shfl_down(s1, off);
    s2 += __shfl_down(s2, off);
  }
  if (lane == 0) { red[wid * 2] = s1; red[wid * 2 + 1] = s2; }
  __syncthreads();
  if (tid == 0) {
    atomicAdd(&sums[0], red[0] + red[2] + red[4] + red[6]);
    atomicAdd(&sums[1], red[1] + red[3] + red[5] + red[7]);
  }
}

// ---------------------------------------------------------------------------
// K2: noise[g] = 0.5*mean + std*N_g  (+ mask dtype probe for fallback path)
// ---------------------------------------------------------------------------
__global__ void k_noise(const void* __restrict__ mask,
                        const double* __restrict__ sums,
                        float* __restrict__ noise, int* __restrict__ mode_p,
                        uint32_t kn0, uint32_t kn1)
{
  const int g = threadIdx.x;
  const double S1 = sums[0], S2 = sums[1];
  const float meanf = (float)(S1 / NTOT);
  const double var = (S2 - S1 * S1 / NTOT) / (NTOT - 1.0);
  const float stdf = (float)sqrt(var);
  const float mean_s = meanf / 10.0f;
  const float std_s  = stdf / 5.0f;

  uint32_t o0, o1;
  threefry2x32(kn0, kn1, 0u, (uint32_t)g, o0, o1);
  uint32_t bits = o0 ^ o1;
  float u = bits_to_u01(bits);
  float v = u * 2.0f + (-0.99999994f);
  v = fmaxf(v, -0.99999994f);
  float wv = -log1pf(-v * v);
  float p;
  if (wv < 5.0f) {
    wv -= 2.5f;
    p = 2.81022636e-08f;
    p = fmaf(p, wv, 3.43273939e-07f);
    p = fmaf(p, wv, -3.5233877e-06f);
    p = fmaf(p, wv, -4.39150654e-06f);
    p = fmaf(p, wv, 0.00021858087f);
    p = fmaf(p, wv, -0.00125372503f);
    p = fmaf(p, wv, -0.00417768164f);
    p = fmaf(p, wv, 0.246640727f);
    p = fmaf(p, wv, 1.50140941f);
  } else {
    wv = sqrtf(wv) - 3.0f;
    p = -0.000200214257f;
    p = fmaf(p, wv, 0.000100950558f);
    p = fmaf(p, wv, 0.00134934322f);
    p = fmaf(p, wv, -0.00367342844f);
    p = fmaf(p, wv, 0.00573950773f);
    p = fmaf(p, wv, -0.0076224613f);
    p = fmaf(p, wv, 0.00943887047f);
    p = fmaf(p, wv, 1.00167406f);
    p = fmaf(p, wv, 2.83297682f);
  }
  const float nrm = 1.41421354f * (p * v);
  noise[g] = mean_s + std_s * nrm - 0.5f * mean_s;

  if (g == 0) *mode_p = probe_mode(mask);
}

// ---------------------------------------------------------------------------
// k_scan: last_start[b][t] via block cummax scan (one block per batch)
// ---------------------------------------------------------------------------
__global__ __launch_bounds__(256) void k_scan(const void* __restrict__ mask,
                                              int* __restrict__ ls)
{
  __shared__ int tm[256];
  __shared__ int smode;
  const int b = blockIdx.x, tid = threadIdx.x;
  if (tid == 0) smode = probe_mode(mask);
  __syncthreads();
  const int mode = smode;
  const long long mb = (long long)b * S_;
  const int base = tid * 16;
  int run = 0;
#pragma unroll
  for (int i = 0; i < 16; ++i) {
    int t = base + i;
    if (t == 0 || mask_at(mask, mode, mb + t - 1)) run = t;
  }
  int cur = run;
  tm[tid] = cur;
  __syncthreads();
  for (int off = 1; off < 256; off <<= 1) {
    int o = (tid >= off) ? tm[tid - off] : 0;
    __syncthreads();
    cur = max(cur, o);
    tm[tid] = cur;
    __syncthreads();
  }
  int pref = (tid > 0) ? tm[tid - 1] : 0;
  run = pref;
#pragma unroll
  for (int i = 0; i < 16; ++i) {
    int t = base + i;
    if (t == 0 || mask_at(mask, mode, mb + t - 1)) run = t;
    ls[mb + t] = run;
  }
}

// ---------------------------------------------------------------------------
// k_addnoise_ls: add noise to segment-start rows only (fixed points)
// ---------------------------------------------------------------------------
__global__ void k_addnoise_ls(float* __restrict__ h,
                              const int* __restrict__ ls,
                              const float* __restrict__ noise)
{
  const long long idx4 = (long long)blockIdx.x * blockDim.x + threadIdx.x;
  const long long row = idx4 >> 5;
  const int t = (int)(row & (S_ - 1));
  if (ls[row] != t) return;
  const int c4 = (int)(idx4 & 31);
  const float4 nv = ((const float4*)noise)[c4];
  float4 v = ((float4*)h)[idx4];
  v.x += nv.x; v.y += nv.y; v.z += nv.z; v.w += nv.w;
  ((float4*)h)[idx4] = v;
}

// ---------------------------------------------------------------------------
// k_gather_ls: non-start rows copy from their (noised) start row. Race-free:
// sources are fixed points, never written.
// ---------------------------------------------------------------------------
__global__ void k_gather_ls(float* __restrict__ h, const int* __restrict__ ls)
{
  const long long row = (long long)blockIdx.x * 8 + (threadIdx.x >> 5);
  const int c4 = threadIdx.x & 31;
  const int t = (int)(row & (S_ - 1));
  const int s = ls[row];
  if (s == t) return;
  const long long b = row >> 12;
  const float4 v = ((const float4*)h)[((b << 12) + s) * 32 + c4];
  ((float4*)h)[row * 32 + c4] = v;
}

// ---------------------------------------------------------------------------
// Fallback (tiny ws): round-0 mask-walk kernels
// ---------------------------------------------------------------------------
__global__ void k_addnoise(float* __restrict__ h, const void* __restrict__ mask,
                           const float* __restrict__ noise,
                           const int* __restrict__ mode_p)
{
  const int mode = *mode_p;
  const long long idx4 = (long long)blockIdx.x * blockDim.x + threadIdx.x;
  const long long row = idx4 >> 5;
  const int t = (int)(row & (S_ - 1));
  const long long b = row >> 12;
  const bool start = (t == 0) || mask_at(mask, mode, b * S_ + t - 1);
  if (!start) return;
  const int c4 = (int)(idx4 & 31);
  const float4 nv = ((const float4*)noise)[c4];
  float4 v = ((float4*)h)[idx4];
  v.x += nv.x; v.y += nv.y; v.z += nv.z; v.w += nv.w;
  ((float4*)h)[idx4] = v;
}

__global__ void k_fill(float* __restrict__ h, const void* __restrict__ mask,
                       const int* __restrict__ mode_p)
{
  const int mode = *mode_p;
  const long long row = (long long)blockIdx.x * 8 + (threadIdx.x >> 5);
  const int lane4 = threadIdx.x & 31;
  const int t = (int)(row & (S_ - 1));
  const long long b = row >> 12;
  const long long mbase = b * S_;
  int s = t;
  while (s > 0 && !mask_at(mask, mode, mbase + s - 1)) --s;
  if (s == t) return;
  const float4 v = ((const float4*)h)[(mbase + s) * 32 + lane4];
  ((float4*)h)[row * 32 + lane4] = v;
}

// ---------------------------------------------------------------------------
// host entry
// ---------------------------------------------------------------------------
extern "C" void kernel_launch(void* const* d_in, const int* in_sizes, int n_in,
                              void* d_out, int out_size, void* d_ws, size_t ws_size,
                              hipStream_t stream)
{
  (void)in_sizes; (void)n_in; (void)out_size;
  const float* x    = (const float*)d_in[0];
  const void*  mask = d_in[1];
  const float* Wm   = (const float*)d_in[2];
  const float* bias = (const float*)d_in[3];
  float* h = (float*)d_out;

  double* sums  = (double*)d_ws;                 // 16 B
  int*    modep = (int*)((char*)d_ws + 16);      // 4 B
  float*  noise = (float*)((char*)d_ws + 32);    // 512 B
  int*    ls    = (int*)((char*)d_ws + 1024);    // 512 KB
  const bool bigws = ws_size >= (size_t)(1024 + MROWS * 4);

  uint32_t kd0, kd1, kn0, kn1;
  threefry2x32(0u, 42u, 0u, 0u, kd0, kd1);
  threefry2x32(0u, 42u, 0u, 1u, kn0, kn1);

  hipMemsetAsync(d_ws, 0, 16, stream);
  if (bigws)
    hipLaunchKernelGGL(k_scan, dim3(B_), dim3(256), 0, stream, mask, ls);
  hipLaunchKernelGGL(k_matmul, dim3(MROWS / 128), dim3(256), 0, stream,
                     x, Wm, bias, h, sums, kd0, kd1);
  hipLaunchKernelGGL(k_noise, dim3(1), dim3(128), 0, stream,
                     mask, sums, noise, modep, kn0, kn1);
  if (bigws) {
    hipLaunchKernelGGL(k_addnoise_ls, dim3((MROWS * 32) / 256), dim3(256), 0, stream,
                       h, ls, noise);
    hipLaunchKernelGGL(k_gather_ls, dim3(MROWS / 8), dim3(256), 0, stream, h, ls);
  } else {
    hipLaunchKernelGGL(k_addnoise, dim3((MROWS * 32) / 256), dim3(256), 0, stream,
                       h, mask, noise, modep);
    hipLaunchKernelGGL(k_fill, dim3(MROWS / 8), dim3(256), 0, stream, h, mask, modep);
  }
}

// Round 5
// 483.420 us; speedup vs baseline: 1.2951x; 1.0779x over previous
//
#include <hip/hip_runtime.h>
#include <stdint.h>
#include <math.h>

#define B_ 32
#define S_ 4096
#define D_ 512
#define G_ 128
#define MROWS (B_ * S_)
#define NTOT (16777216.0)

typedef __attribute__((ext_vector_type(8))) short bf16x8;
typedef __attribute__((ext_vector_type(4))) float f32x4;

// ---------------------------------------------------------------------------
// threefry2x32 — matches JAX exactly
// ---------------------------------------------------------------------------
__host__ __device__ __forceinline__ uint32_t rotl32(uint32_t x, int r) {
  return (x << r) | (x >> (32 - r));
}

__host__ __device__ __forceinline__ void threefry2x32(
    uint32_t k0, uint32_t k1, uint32_t x0, uint32_t x1,
    uint32_t& o0, uint32_t& o1) {
  const uint32_t ks2 = k0 ^ k1 ^ 0x1BD11BDAu;
  uint32_t v0 = x0 + k0;
  uint32_t v1 = x1 + k1;
#define TF_RND(r) { v0 += v1; v1 = rotl32(v1, (r)); v1 ^= v0; }
  TF_RND(13) TF_RND(15) TF_RND(26) TF_RND(6)
  v0 += k1;  v1 += ks2 + 1u;
  TF_RND(17) TF_RND(29) TF_RND(16) TF_RND(24)
  v0 += ks2; v1 += k0 + 2u;
  TF_RND(13) TF_RND(15) TF_RND(26) TF_RND(6)
  v0 += k0;  v1 += k1 + 3u;
  TF_RND(17) TF_RND(29) TF_RND(16) TF_RND(24)
  v0 += k1;  v1 += ks2 + 4u;
  TF_RND(13) TF_RND(15) TF_RND(26) TF_RND(6)
  v0 += ks2; v1 += k0 + 5u;
#undef TF_RND
  o0 = v0; o1 = v1;
}

__device__ __forceinline__ float bits_to_u01(uint32_t bits) {
  return __uint_as_float((bits >> 9) | 0x3f800000u) - 1.0f;
}

// keep iff u01(bits) < 0.9f  ⟺  (bits>>9) < 7549747  (0.9f = 7549747*2^-23)
// kept value: x * (1/0.9) — ≤1 ulp from XLA's divide, invisible vs tolerance
__device__ __forceinline__ float drop_scale(uint32_t kd0, uint32_t kd1,
                                            uint32_t j, float xv) {
  uint32_t o0, o1;
  threefry2x32(kd0, kd1, 0u, j, o0, o1);
  uint32_t m = (o0 ^ o1) >> 9;
  return (m < 7549747u) ? xv * 1.11111116f : 0.0f;
}

// cheap bf16 split: hi = truncate-to-bf16 (1 AND), lo = RNE(v - hi).
// dropped al*bl term goes 2^-18 -> 2^-17 relative: invisible vs tolerance.
__device__ __forceinline__ void split_bf16(float v, ushort& hh, ushort& ll) {
  uint32_t u = __float_as_uint(v);
  hh = (ushort)(u >> 16);
  float lf = v - __uint_as_float(u & 0xFFFF0000u);  // exact
  uint32_t ul = __float_as_uint(lf);
  ll = (ushort)((ul + 0x7FFFu + ((ul >> 16) & 1u)) >> 16);
}

// ---------------------------------------------------------------------------
// critic_mask dtype-agnostic accessor (mode: 0=int32, 1=uint8/bool, 2=float32)
// ---------------------------------------------------------------------------
__device__ __forceinline__ bool mask_at(const void* m, int mode, long long i) {
  if (mode == 0) return ((const int*)m)[i] != 0;
  if (mode == 1) return ((const unsigned char*)m)[i] != 0;
  return ((const float*)m)[i] != 0.0f;
}

// ---------------------------------------------------------------------------
// K1: h = dropout(x) @ W^T + b via bf16 3-pass split MFMA; f64 sum/sumsq.
// BM=128, BN=128(=G), BK=32; 256 threads = 4 waves, each wave 64x64 out.
// ---------------------------------------------------------------------------
__global__ __launch_bounds__(256, 3) void k_matmul(
    const float* __restrict__ x, const float* __restrict__ Wm,
    const float* __restrict__ bias, float* __restrict__ h,
    double* __restrict__ sums, uint32_t kd0, uint32_t kd1)
{
  __shared__ ushort AsH[128][40];   // [row][k] pad 32->40 (2-way max conflict)
  __shared__ ushort AsL[128][40];
  __shared__ ushort BsH[128][40];   // [g][k]
  __shared__ ushort BsL[128][40];
  __shared__ double red[8];

  const int tid = threadIdx.x;
  const long long row0 = (long long)blockIdx.x * 128;

  f32x4 acc[4][4];
#pragma unroll
  for (int m = 0; m < 4; ++m)
#pragma unroll
    for (int n = 0; n < 4; ++n) acc[m][n] = (f32x4)0.0f;

  // staging mapping: 2 threads per row, 16 k each
  const int arow = tid >> 1;
  const int ak0  = (tid & 1) << 4;
  const float* xrow = x + (row0 + arow) * D_ + ak0;
  const float* wrow = Wm + arow * D_ + ak0;
  const uint32_t jrow = (uint32_t)((row0 + arow) * D_) + (uint32_t)ak0;

  // compute mapping
  const int lane = tid & 63;
  const int wid  = tid >> 6;
  const int rbw  = (wid >> 1) * 64;
  const int cbw  = (wid & 1) * 64;
  const int lr   = lane & 15;
  const int lk   = (lane >> 4) * 8;

  float4 ax0, ax1, ax2, ax3, wx0, wx1, wx2, wx3;
#define LOADT(kc) { \
    const float4* xp = (const float4*)(xrow + (kc)); \
    const float4* wp = (const float4*)(wrow + (kc)); \
    ax0 = xp[0]; ax1 = xp[1]; ax2 = xp[2]; ax3 = xp[3]; \
    wx0 = wp[0]; wx1 = wp[1]; wx2 = wp[2]; wx3 = wp[3]; }

#define PROCA(xv, i4, kc) { \
    uint32_t jb = jrow + (uint32_t)(kc) + (uint32_t)((i4) * 4); \
    float v0 = drop_scale(kd0, kd1, jb + 0u, (xv).x); \
    float v1 = drop_scale(kd0, kd1, jb + 1u, (xv).y); \
    float v2 = drop_scale(kd0, kd1, jb + 2u, (xv).z); \
    float v3 = drop_scale(kd0, kd1, jb + 3u, (xv).w); \
    ushort h0,l0,h1,l1,h2,l2,h3,l3; \
    split_bf16(v0,h0,l0); split_bf16(v1,h1,l1); \
    split_bf16(v2,h2,l2); split_bf16(v3,h3,l3); \
    *(ushort4*)&AsH[arow][ak0 + (i4)*4] = make_ushort4(h0,h1,h2,h3); \
    *(ushort4*)&AsL[arow][ak0 + (i4)*4] = make_ushort4(l0,l1,l2,l3); }

#define PROCW(wv, i4) { \
    ushort h0,l0,h1,l1,h2,l2,h3,l3; \
    split_bf16((wv).x,h0,l0); split_bf16((wv).y,h1,l1); \
    split_bf16((wv).z,h2,l2); split_bf16((wv).w,h3,l3); \
    *(ushort4*)&BsH[arow][ak0 + (i4)*4] = make_ushort4(h0,h1,h2,h3); \
    *(ushort4*)&BsL[arow][ak0 + (i4)*4] = make_ushort4(l0,l1,l2,l3); }

  LOADT(0);
  for (int kc = 0; kc < D_; kc += 32) {
    // stage current chunk (threefry dropout on A; hi/lo split both)
    PROCA(ax0, 0, kc) PROCA(ax1, 1, kc) PROCA(ax2, 2, kc) PROCA(ax3, 3, kc)
    PROCW(wx0, 0) PROCW(wx1, 1) PROCW(wx2, 2) PROCW(wx3, 3)
    __syncthreads();
    if (kc + 32 < D_) LOADT(kc + 32);   // issue next-chunk loads early

    bf16x8 ah[4], al[4], bh[4], bl[4];
#pragma unroll
    for (int m = 0; m < 4; ++m) {
      ah[m] = *(const bf16x8*)&AsH[rbw + m * 16 + lr][lk];
      al[m] = *(const bf16x8*)&AsL[rbw + m * 16 + lr][lk];
    }
#pragma unroll
    for (int n = 0; n < 4; ++n) {
      bh[n] = *(const bf16x8*)&BsH[cbw + n * 16 + lr][lk];
      bl[n] = *(const bf16x8*)&BsL[cbw + n * 16 + lr][lk];
    }
#pragma unroll
    for (int m = 0; m < 4; ++m)
#pragma unroll
      for (int n = 0; n < 4; ++n) {
        acc[m][n] = __builtin_amdgcn_mfma_f32_16x16x32_bf16(ah[m], bh[n], acc[m][n], 0, 0, 0);
        acc[m][n] = __builtin_amdgcn_mfma_f32_16x16x32_bf16(ah[m], bl[n], acc[m][n], 0, 0, 0);
        acc[m][n] = __builtin_amdgcn_mfma_f32_16x16x32_bf16(al[m], bh[n], acc[m][n], 0, 0, 0);
      }
    __syncthreads();
  }
#undef LOADT
#undef PROCA
#undef PROCW

  // epilogue: +bias, store, f64 sums. C/D layout: col=lane&15, row=(lane>>4)*4+reg
  double s1 = 0.0, s2 = 0.0;
  const int orow_q = (lane >> 4) * 4;
  float bn[4];
#pragma unroll
  for (int n = 0; n < 4; ++n) bn[n] = bias[cbw + n * 16 + lr];
#pragma unroll
  for (int m = 0; m < 4; ++m) {
#pragma unroll
    for (int n = 0; n < 4; ++n) {
#pragma unroll
      for (int r = 0; r < 4; ++r) {
        const long long grow = row0 + rbw + m * 16 + orow_q + r;
        float v = acc[m][n][r] + bn[n];
        h[grow * G_ + cbw + n * 16 + lr] = v;
        s1 += (double)v;
        s2 += (double)v * (double)v;
      }
    }
  }
#pragma unroll
  for (int off = 32; off > 0; off >>= 1) {
    s1 += __shfl_down(s1, off);
    s2 += __shfl_down(s2, off);
  }
  if (lane == 0) { red[wid * 2] = s1; red[wid * 2 + 1] = s2; }
  __syncthreads();
  if (tid == 0) {
    atomicAdd(&sums[0], red[0] + red[2] + red[4] + red[6]);
    atomicAdd(&sums[1], red[1] + red[3] + red[5] + red[7]);
  }
}

// ---------------------------------------------------------------------------
// K2: noise[g] = 0.5*mean + std*N_g  (+ ballot-parallel mask dtype probe)
// ---------------------------------------------------------------------------
__global__ void k_noise(const void* __restrict__ mask,
                        const double* __restrict__ sums,
                        float* __restrict__ noise, int* __restrict__ mode_p,
                        uint32_t kn0, uint32_t kn1)
{
  const int g = threadIdx.x;
  const double S1 = sums[0], S2 = sums[1];
  const float meanf = (float)(S1 / NTOT);
  const double var = (S2 - S1 * S1 / NTOT) / (NTOT - 1.0);
  const float stdf = (float)sqrt(var);
  const float mean_s = meanf / 10.0f;
  const float std_s  = stdf / 5.0f;

  uint32_t o0, o1;
  threefry2x32(kn0, kn1, 0u, (uint32_t)g, o0, o1);
  uint32_t bits = o0 ^ o1;
  float u = bits_to_u01(bits);
  float v = u * 2.0f + (-0.99999994f);
  v = fmaxf(v, -0.99999994f);
  float wv = -log1pf(-v * v);
  float p;
  if (wv < 5.0f) {
    wv -= 2.5f;
    p = 2.81022636e-08f;
    p = fmaf(p, wv, 3.43273939e-07f);
    p = fmaf(p, wv, -3.5233877e-06f);
    p = fmaf(p, wv, -4.39150654e-06f);
    p = fmaf(p, wv, 0.00021858087f);
    p = fmaf(p, wv, -0.00125372503f);
    p = fmaf(p, wv, -0.00417768164f);
    p = fmaf(p, wv, 0.246640727f);
    p = fmaf(p, wv, 1.50140941f);
  } else {
    wv = sqrtf(wv) - 3.0f;
    p = -0.000200214257f;
    p = fmaf(p, wv, 0.000100950558f);
    p = fmaf(p, wv, 0.00134934322f);
    p = fmaf(p, wv, -0.00367342844f);
    p = fmaf(p, wv, 0.00573950773f);
    p = fmaf(p, wv, -0.0076224613f);
    p = fmaf(p, wv, 0.00943887047f);
    p = fmaf(p, wv, 1.00167406f);
    p = fmaf(p, wv, 2.83297682f);
  }
  const float nrm = 1.41421354f * (p * v);
  noise[g] = mean_s + std_s * nrm - 0.5f * mean_s;

  if (g < 64) {  // wave-0 ballot probe of critic_mask storage dtype
    uint32_t w = ((const uint32_t*)mask)[g];
    unsigned long long b01 = __ballot(w > 1u);
    unsigned long long bfl = __ballot(w != 0u && w != 0x3f800000u);
    if (g == 0) *mode_p = (b01 == 0ull) ? 0 : ((bfl == 0ull) ? 2 : 1);
  }
}

// ---------------------------------------------------------------------------
// K3: add noise to segment-START rows only (in place). Start rows stay fixed
// points for K4's gather -> race-free in-place forward-fill.
// ---------------------------------------------------------------------------
__global__ void k_addnoise(float* __restrict__ h, const void* __restrict__ mask,
                           const float* __restrict__ noise,
                           const int* __restrict__ mode_p)
{
  const int mode = *mode_p;
  const long long idx4 = (long long)blockIdx.x * blockDim.x + threadIdx.x;
  const long long row = idx4 >> 5;        // 32 float4 per row of G=128
  const int t = (int)(row & (S_ - 1));
  const long long b = row >> 12;
  const bool start = (t == 0) || mask_at(mask, mode, b * S_ + t - 1);
  if (!start) return;
  const int c4 = (int)(idx4 & 31);
  const float4 nv = ((const float4*)noise)[c4];
  float4 v = ((float4*)h)[idx4];
  v.x += nv.x; v.y += nv.y; v.z += nv.z; v.w += nv.w;
  ((float4*)h)[idx4] = v;
}

// ---------------------------------------------------------------------------
// K4: forward-fill gather with IN-BLOCK last_start scan (no workspace).
// Block = (batch, 64-row chunk). Wave 0: start flags -> wave max-scan ->
// ballot backward carry search (expected 1 iter). Then coalesced gather.
// ---------------------------------------------------------------------------
__global__ __launch_bounds__(256) void k_fill2(float* __restrict__ h,
                                               const void* __restrict__ mask,
                                               const int* __restrict__ mode_p)
{
  __shared__ int ls_s[64];
  const int mode = *mode_p;
  const int bidx = blockIdx.x;
  const int b = bidx >> 6;             // 64 chunks per batch
  const int t0 = (bidx & 63) << 6;     // chunk * 64
  const long long mb = (long long)b * S_;
  const int tid = threadIdx.x;

  if (tid < 64) {
    const int lane = tid;
    const int t = t0 + lane;
    const bool flag = (t == 0) || mask_at(mask, mode, mb + t - 1);
    int val = flag ? t : -1;
    // inclusive max-scan across the wave (Hillis-Steele)
#pragma unroll
    for (int off = 1; off < 64; off <<= 1) {
      int v2 = __shfl_up(val, off);
      if (lane >= off) val = max(val, v2);
    }
    unsigned long long need = __ballot(val == -1);
    if (need) {  // uniform across wave
      int carry = 0;
      for (int w = 1;; ++w) {
        const int tp = t0 - (w << 6) + lane;
        const bool fp = (tp == 0) || (tp > 0 && mask_at(mask, mode, mb + tp - 1));
        unsigned long long bal = __ballot(fp);
        if (bal) { carry = t0 - (w << 6) + (63 - __clzll(bal)); break; }
      }
      if (val == -1) val = carry;
    }
    ls_s[lane] = val;
  }
  __syncthreads();

  float4* h4 = (float4*)h;
  const int c4 = tid & 31;
  const int rbase = tid >> 5;          // 0..7
#pragma unroll
  for (int it = 0; it < 8; ++it) {
    const int rl = rbase + it * 8;
    const int s = ls_s[rl];
    const int t = t0 + rl;
    if (s != t)
      h4[(mb + t) * 32 + c4] = h4[(mb + s) * 32 + c4];
  }
}

// ---------------------------------------------------------------------------
// host entry
// ---------------------------------------------------------------------------
extern "C" void kernel_launch(void* const* d_in, const int* in_sizes, int n_in,
                              void* d_out, int out_size, void* d_ws, size_t ws_size,
                              hipStream_t stream)
{
  (void)in_sizes; (void)n_in; (void)out_size; (void)ws_size;
  const float* x    = (const float*)d_in[0];
  const void*  mask = d_in[1];
  const float* Wm   = (const float*)d_in[2];
  const float* bias = (const float*)d_in[3];
  float* h = (float*)d_out;

  double* sums  = (double*)d_ws;                 // 16 B
  int*    modep = (int*)((char*)d_ws + 16);      // 4 B
  float*  noise = (float*)((char*)d_ws + 32);    // 512 B

  uint32_t kd0, kd1, kn0, kn1;
  threefry2x32(0u, 42u, 0u, 0u, kd0, kd1);   // kd = split(key(42))[0]
  threefry2x32(0u, 42u, 0u, 1u, kn0, kn1);   // kn = split(key(42))[1]

  hipMemsetAsync(d_ws, 0, 16, stream);
  hipLaunchKernelGGL(k_matmul, dim3(MROWS / 128), dim3(256), 0, stream,
                     x, Wm, bias, h, sums, kd0, kd1);
  hipLaunchKernelGGL(k_noise, dim3(1), dim3(128), 0, stream,
                     mask, sums, noise, modep, kn0, kn1);
  hipLaunchKernelGGL(k_addnoise, dim3((MROWS * 32) / 256), dim3(256), 0, stream,
                     h, mask, noise, modep);
  hipLaunchKernelGGL(k_fill2, dim3(B_ * 64), dim3(256), 0, stream,
                     h, mask, modep);
}